// Round 7
// baseline (238.422 us; speedup 1.0000x reference)
//
#include <hip/hip_runtime.h>
#include <hip/hip_cooperative_groups.h>

namespace cg = cooperative_groups;

#define NN 10000
#define NE 320000
#define CAP 96
#define CBLK 512
#define CTHR 512
#define CTOT (CBLK * CTHR) /* 262144 threads */
#define CWAVES (CBLK * 8)  /* 4096 waves */

typedef __bf16 bf16x8 __attribute__((ext_vector_type(8)));
typedef float f32x4 __attribute__((ext_vector_type(4)));
typedef unsigned short us8 __attribute__((ext_vector_type(8)));

static __device__ __forceinline__ unsigned short f2bf(float f) {
  union { float fv; unsigned u; } v; v.fv = f;
  unsigned r = v.u + 0x7FFFu + ((v.u >> 16) & 1u);
  return (unsigned short)(r >> 16);
}
static __device__ __forceinline__ float bf2f(unsigned short b) {
  union { unsigned u; float f; } v; v.u = ((unsigned)b) << 16;
  return v.f;
}

// ======================= cooperative mega-kernel ===========================
// 512 blocks x 512 threads, all co-resident (2 blocks/CU: LDS 37.4KB x2,
// VGPR<=128 via __launch_bounds__(512,4)). 4 phases split by grid.sync().

__global__ __launch_bounds__(CTHR, 4) void mega2_k(
    const float* __restrict__ x, const int* __restrict__ ei,
    const float* __restrict__ w1, const float* __restrict__ b1,
    const float* __restrict__ w2, const float* __restrict__ b2,
    const float* __restrict__ epsp, float* __restrict__ out,
    int* __restrict__ cnt, int* __restrict__ bucket,
    unsigned short* __restrict__ xb, unsigned short* __restrict__ w1t,
    unsigned short* __restrict__ w2t, unsigned short* __restrict__ hb) {
  __shared__ unsigned short AsM[32][264];  // 16.9 KB (P3 A-tile; P1 scratch)
  __shared__ unsigned short Bs[256][40];   // 20.5 KB (P3 weight chunk, K=32)
  cg::grid_group grid = cg::this_grid();
  const int tid = threadIdx.x;
  const int bid = blockIdx.x;
  const int gtid = bid * CTHR + tid;

  // ---------------- P0: zero cnt + convert x -> bf16 ----------------
  if (gtid < 10240) cnt[gtid] = 0;
  for (int t = gtid; t < 640000; t += CTOT) {
    float4 v = reinterpret_cast<const float4*>(x)[t];
    ushort4 o;
    o.x = f2bf(v.x); o.y = f2bf(v.y); o.z = f2bf(v.z); o.w = f2bf(v.w);
    reinterpret_cast<ushort4*>(xb)[t] = o;
  }
  grid.sync();

  // ---------------- P1: bucket fill (4 edges/thread) + W transpose ---------
  if (gtid < NE / 4) {
    int e = gtid * 4;
    int4 s = *reinterpret_cast<const int4*>(&ei[e]);
    int4 d = *reinterpret_cast<const int4*>(&ei[NE + e]);
    int p;
    p = atomicAdd(&cnt[d.x], 1); if (p < CAP) bucket[d.x * CAP + p] = s.x;
    p = atomicAdd(&cnt[d.y], 1); if (p < CAP) bucket[d.y * CAP + p] = s.y;
    p = atomicAdd(&cnt[d.z], 1); if (p < CAP) bucket[d.z * CAP + p] = s.z;
    p = atomicAdd(&cnt[d.w], 1); if (p < CAP) bucket[d.w * CAP + p] = s.w;
  }
  if (bid >= CBLK - 32) {  // 32 transpose tiles on blocks idle in fill
    unsigned short* sh = &AsM[0][0];  // used as [64][72]
    int b2 = bid - (CBLK - 32);
    const float* w = (b2 & 16) ? w2 : w1;
    unsigned short* wt = (b2 & 16) ? w2t : w1t;
    int tile = b2 & 15;
    int ki0 = (tile >> 2) * 64, ni0 = (tile & 3) * 64;
    if (tid < 256) {
      int r = tid >> 4, c = tid & 15;
#pragma unroll
      for (int rr = r; rr < 64; rr += 16) {
        float4 v = *reinterpret_cast<const float4*>(&w[(ki0 + rr) * 256 + ni0 + c * 4]);
        ushort4 o;
        o.x = f2bf(v.x); o.y = f2bf(v.y); o.z = f2bf(v.z); o.w = f2bf(v.w);
        *reinterpret_cast<ushort4*>(&sh[rr * 72 + c * 4]) = o;
      }
    }
    __syncthreads();
    if (tid < 256) {
      int nidx = tid >> 3, c8 = tid & 7;
#pragma unroll
      for (int nn2 = nidx; nn2 < 64; nn2 += 32) {
        us8 o;
#pragma unroll
        for (int j = 0; j < 8; ++j) o[j] = sh[(c8 * 8 + j) * 72 + nn2];
        *reinterpret_cast<us8*>(&wt[(ni0 + nn2) * 256 + ki0 + c8 * 8]) = o;
      }
    }
  }
  grid.sync();

  // ---------------- P2: aggregation (2 rows/load, index prefetch) ----------
  {
    const us8* xb8 = (const us8*)xb;
    int wv = (bid << 3) + (tid >> 6);
    int lane = tid & 63;
    int half = lane >> 5, off = lane & 31;
    float e1 = 1.0f + epsp[0];
    float selfw = half ? 0.0f : e1;
    for (int node = wv; node < NN; node += CWAVES) {
      us8 sv = xb8[node * 32 + off];
      float a[8];
#pragma unroll
      for (int j = 0; j < 8; ++j) a[j] = bf2f(sv[j]) * selfw;
      int n = min(cnt[node], CAP);
      const int4* bp4 = (const int4*)(bucket + node * CAP);
      int4 ia = bp4[0], ib = bp4[1];
      int k = 0;
      while (k + 8 <= n) {
        int4 na = bp4[(k >> 2) + 2];  // prefetch next 8 indices (pad-safe)
        int4 nb = bp4[(k >> 2) + 3];
        int r0 = half ? ia.y : ia.x;
        int r1 = half ? ia.w : ia.z;
        int r2 = half ? ib.y : ib.x;
        int r3 = half ? ib.w : ib.z;
        us8 v0 = xb8[r0 * 32 + off];
        us8 v1 = xb8[r1 * 32 + off];
        us8 v2 = xb8[r2 * 32 + off];
        us8 v3 = xb8[r3 * 32 + off];
#pragma unroll
        for (int j = 0; j < 8; ++j)
          a[j] += (bf2f(v0[j]) + bf2f(v1[j])) + (bf2f(v2[j]) + bf2f(v3[j]));
        ia = na; ib = nb; k += 8;
      }
      int tl = n - k;  // 0..7 remaining, indices live in ia/ib
#pragma unroll
      for (int p = 0; p < 4; ++p) {
        int idx = (p == 0) ? (half ? ia.y : ia.x)
                : (p == 1) ? (half ? ia.w : ia.z)
                : (p == 2) ? (half ? ib.y : ib.x)
                           : (half ? ib.w : ib.z);
        if (2 * p + half < tl) {
          us8 v = xb8[idx * 32 + off];
#pragma unroll
          for (int j = 0; j < 8; ++j) a[j] += bf2f(v[j]);
        }
      }
#pragma unroll
      for (int j = 0; j < 8; ++j) a[j] += __shfl_xor(a[j], 32);
      if (half == 0) {
        us8 o;
#pragma unroll
        for (int j = 0; j < 8; ++j) o[j] = f2bf(a[j]);
        *reinterpret_cast<us8*>(&hb[node * 256 + off * 8]) = o;
      }
    }
  }
  grid.sync();

  // ---------------- P3: MLP, 32-row tiles, 8 waves (2M x 4N) ---------------
  if (bid < (NN + 31) / 32) {
    int m0 = bid * 32;
    int lane = tid & 63, wave = tid >> 6;
    int waveM = wave & 1, waveN = wave >> 1;
    int l15 = lane & 15, g = lane >> 4;
#pragma unroll
    for (int i = 0; i < 2; ++i) {  // stage A: 1024 int4, 2/thread
      int idx = tid + i * CTHR;
      int r = idx >> 5, c8 = idx & 31;
      int row = m0 + r;
      int4 v = (row < NN) ? *reinterpret_cast<const int4*>(&hb[row * 256 + c8 * 8])
                          : make_int4(0, 0, 0, 0);
      *reinterpret_cast<int4*>(&AsM[r][c8 * 8]) = v;
    }
    float bias1[4], bias2[4];
#pragma unroll
    for (int ni = 0; ni < 4; ++ni) {
      int col = waveN * 64 + ni * 16 + l15;
      bias1[ni] = b1[col];
      bias2[ni] = b2[col];
    }
    f32x4 acc[4];
#pragma unroll
    for (int ni = 0; ni < 4; ++ni) acc[ni] = f32x4{0.f, 0.f, 0.f, 0.f};

    for (int k0 = 0; k0 < 256; k0 += 32) {  // GEMM1
#pragma unroll
      for (int i = 0; i < 2; ++i) {
        int idx = tid + i * CTHR;
        int nrow = idx >> 2, kc = idx & 3;
        *reinterpret_cast<int4*>(&Bs[nrow][kc * 8]) =
            *reinterpret_cast<const int4*>(&w1t[nrow * 256 + k0 + kc * 8]);
      }
      __syncthreads();
      bf16x8 af = *reinterpret_cast<const bf16x8*>(&AsM[waveM * 16 + l15][k0 + g * 8]);
#pragma unroll
      for (int ni = 0; ni < 4; ++ni) {
        bf16x8 bfr = *reinterpret_cast<const bf16x8*>(
            &Bs[waveN * 64 + ni * 16 + l15][g * 8]);
        acc[ni] = __builtin_amdgcn_mfma_f32_16x16x32_bf16(af, bfr, acc[ni], 0, 0, 0);
      }
      __syncthreads();
    }
#pragma unroll
    for (int ni = 0; ni < 4; ++ni) {  // relu back into AsM
      int col = waveN * 64 + ni * 16 + l15;
#pragma unroll
      for (int r = 0; r < 4; ++r)
        AsM[waveM * 16 + g * 4 + r][col] = f2bf(fmaxf(acc[ni][r] + bias1[ni], 0.f));
      acc[ni] = f32x4{0.f, 0.f, 0.f, 0.f};
    }
    for (int k0 = 0; k0 < 256; k0 += 32) {  // GEMM2
#pragma unroll
      for (int i = 0; i < 2; ++i) {
        int idx = tid + i * CTHR;
        int nrow = idx >> 2, kc = idx & 3;
        *reinterpret_cast<int4*>(&Bs[nrow][kc * 8]) =
            *reinterpret_cast<const int4*>(&w2t[nrow * 256 + k0 + kc * 8]);
      }
      __syncthreads();
      bf16x8 af = *reinterpret_cast<const bf16x8*>(&AsM[waveM * 16 + l15][k0 + g * 8]);
#pragma unroll
      for (int ni = 0; ni < 4; ++ni) {
        bf16x8 bfr = *reinterpret_cast<const bf16x8*>(
            &Bs[waveN * 64 + ni * 16 + l15][g * 8]);
        acc[ni] = __builtin_amdgcn_mfma_f32_16x16x32_bf16(af, bfr, acc[ni], 0, 0, 0);
      }
      __syncthreads();
    }
#pragma unroll
    for (int ni = 0; ni < 4; ++ni) {  // epilogue
      int col = waveN * 64 + ni * 16 + l15;
#pragma unroll
      for (int r = 0; r < 4; ++r) {
        int row = m0 + waveM * 16 + g * 4 + r;
        if (row < NN) out[row * 256 + col] = acc[ni][r] + bias2[ni];
      }
    }
  }
}

// ======================= fallback path (validated r3-r5 kernels) ===========

__global__ __launch_bounds__(256) void conv_k(const float* __restrict__ x,
                                              const float* __restrict__ w1,
                                              const float* __restrict__ w2,
                                              ushort4* __restrict__ xb4,
                                              unsigned short* __restrict__ w1t,
                                              unsigned short* __restrict__ w2t,
                                              int* __restrict__ cnt) {
  __shared__ unsigned short sh[64][72];
  int bid = blockIdx.x, tid = threadIdx.x;
  if (bid < 2500) {
    int t = bid * 256 + tid;
    if (t < 10240) cnt[t] = 0;
    float4 v = reinterpret_cast<const float4*>(x)[t];
    ushort4 o;
    o.x = f2bf(v.x); o.y = f2bf(v.y); o.z = f2bf(v.z); o.w = f2bf(v.w);
    xb4[t] = o;
  } else {
    int b2 = bid - 2500;
    const float* w = (b2 & 16) ? w2 : w1;
    unsigned short* wt = (b2 & 16) ? w2t : w1t;
    int tile = b2 & 15;
    int ki0 = (tile >> 2) * 64, ni0 = (tile & 3) * 64;
    int r = tid >> 4, c = tid & 15;
#pragma unroll
    for (int rr = r; rr < 64; rr += 16) {
      float4 v = *reinterpret_cast<const float4*>(&w[(ki0 + rr) * 256 + ni0 + c * 4]);
      ushort4 o;
      o.x = f2bf(v.x); o.y = f2bf(v.y); o.z = f2bf(v.z); o.w = f2bf(v.w);
      *reinterpret_cast<ushort4*>(&sh[rr][c * 4]) = o;
    }
    __syncthreads();
    int n = tid >> 3, c8 = tid & 7;
#pragma unroll
    for (int nn = n; nn < 64; nn += 32) {
      us8 o;
#pragma unroll
      for (int j = 0; j < 8; ++j) o[j] = sh[c8 * 8 + j][nn];
      *reinterpret_cast<us8*>(&wt[(ni0 + nn) * 256 + ki0 + c8 * 8]) = o;
    }
  }
}

__global__ __launch_bounds__(256) void fill_k(const int* __restrict__ ei,
                                              int* __restrict__ cnt,
                                              int* __restrict__ bucket) {
  int e = (blockIdx.x * 256 + threadIdx.x) * 4;
  if (e < NE) {
    int4 s = *reinterpret_cast<const int4*>(&ei[e]);
    int4 d = *reinterpret_cast<const int4*>(&ei[NE + e]);
    int p;
    p = atomicAdd(&cnt[d.x], 1); if (p < CAP) bucket[d.x * CAP + p] = s.x;
    p = atomicAdd(&cnt[d.y], 1); if (p < CAP) bucket[d.y * CAP + p] = s.y;
    p = atomicAdd(&cnt[d.z], 1); if (p < CAP) bucket[d.z * CAP + p] = s.z;
    p = atomicAdd(&cnt[d.w], 1); if (p < CAP) bucket[d.w * CAP + p] = s.w;
  }
}

__global__ __launch_bounds__(256) void agg_k(const ushort4* __restrict__ xb4,
                                             const int* __restrict__ cnt,
                                             const int* __restrict__ bucket,
                                             const float* __restrict__ epsp,
                                             unsigned short* __restrict__ hb) {
  int node = blockIdx.x * 4 + (threadIdx.x >> 6);
  if (node >= NN) return;
  int lane = threadIdx.x & 63;
  ushort4 s = xb4[node * 64 + lane];
  float e1 = 1.0f + epsp[0];
  float a0 = bf2f(s.x) * e1, a1 = bf2f(s.y) * e1;
  float a2 = bf2f(s.z) * e1, a3 = bf2f(s.w) * e1;
  int n = min(cnt[node], CAP);
  const int* bp = bucket + node * CAP;
  int k = 0;
  for (; k + 3 < n; k += 4) {
    int i0 = bp[k], i1 = bp[k + 1], i2 = bp[k + 2], i3 = bp[k + 3];
    ushort4 v0 = xb4[i0 * 64 + lane];
    ushort4 v1 = xb4[i1 * 64 + lane];
    ushort4 v2 = xb4[i2 * 64 + lane];
    ushort4 v3 = xb4[i3 * 64 + lane];
    a0 += (bf2f(v0.x) + bf2f(v1.x)) + (bf2f(v2.x) + bf2f(v3.x));
    a1 += (bf2f(v0.y) + bf2f(v1.y)) + (bf2f(v2.y) + bf2f(v3.y));
    a2 += (bf2f(v0.z) + bf2f(v1.z)) + (bf2f(v2.z) + bf2f(v3.z));
    a3 += (bf2f(v0.w) + bf2f(v1.w)) + (bf2f(v2.w) + bf2f(v3.w));
  }
  for (; k < n; ++k) {
    ushort4 v0 = xb4[bp[k] * 64 + lane];
    a0 += bf2f(v0.x); a1 += bf2f(v0.y); a2 += bf2f(v0.z); a3 += bf2f(v0.w);
  }
  ushort4 o;
  o.x = f2bf(a0); o.y = f2bf(a1); o.z = f2bf(a2); o.w = f2bf(a3);
  reinterpret_cast<ushort4*>(hb)[node * 64 + lane] = o;
}

__global__ __launch_bounds__(256) void mlp_k(const unsigned short* __restrict__ hb,
                                             const unsigned short* __restrict__ w1t,
                                             const float* __restrict__ b1,
                                             const unsigned short* __restrict__ w2t,
                                             const float* __restrict__ b2,
                                             float* __restrict__ out) {
  __shared__ unsigned short As[32][264];
  __shared__ unsigned short Bs[256][72];
  int m0 = blockIdx.x * 32;
  int tid = threadIdx.x;
  int lane = tid & 63, wave = tid >> 6;
  int waveM = wave & 1, waveN = wave >> 1;
  int l15 = lane & 15, g = lane >> 4;
#pragma unroll
  for (int i = 0; i < 4; ++i) {
    int c = tid + i * 256;
    int r = c >> 5, cc = c & 31;
    int4 v = (m0 + r < NN)
                 ? *reinterpret_cast<const int4*>(&hb[(m0 + r) * 256 + cc * 8])
                 : make_int4(0, 0, 0, 0);
    *reinterpret_cast<int4*>(&As[r][cc * 8]) = v;
  }
  float bias1[8], bias2[8];
#pragma unroll
  for (int ni = 0; ni < 8; ++ni) {
    int col = waveN * 128 + ni * 16 + l15;
    bias1[ni] = b1[col];
    bias2[ni] = b2[col];
  }
  f32x4 acc[8];
#pragma unroll
  for (int ni = 0; ni < 8; ++ni) acc[ni] = f32x4{0.f, 0.f, 0.f, 0.f};
  for (int k0 = 0; k0 < 256; k0 += 64) {
#pragma unroll
    for (int i = 0; i < 8; ++i) {
      int c = tid + i * 256;
      int n = c >> 3, kc = c & 7;
      *reinterpret_cast<int4*>(&Bs[n][kc * 8]) =
          *reinterpret_cast<const int4*>(&w1t[n * 256 + k0 + kc * 8]);
    }
    __syncthreads();
#pragma unroll
    for (int kk = 0; kk < 2; ++kk) {
      bf16x8 af = *reinterpret_cast<const bf16x8*>(
          &As[waveM * 16 + l15][k0 + kk * 32 + g * 8]);
#pragma unroll
      for (int ni = 0; ni < 8; ++ni) {
        bf16x8 bfr = *reinterpret_cast<const bf16x8*>(
            &Bs[waveN * 128 + ni * 16 + l15][kk * 32 + g * 8]);
        acc[ni] = __builtin_amdgcn_mfma_f32_16x16x32_bf16(af, bfr, acc[ni], 0, 0, 0);
      }
    }
    __syncthreads();
  }
#pragma unroll
  for (int ni = 0; ni < 8; ++ni) {
    int col = waveN * 128 + ni * 16 + l15;
#pragma unroll
    for (int r = 0; r < 4; ++r) {
      int row = waveM * 16 + g * 4 + r;
      As[row][col] = f2bf(fmaxf(acc[ni][r] + bias1[ni], 0.f));
    }
    acc[ni] = f32x4{0.f, 0.f, 0.f, 0.f};
  }
  for (int k0 = 0; k0 < 256; k0 += 64) {
#pragma unroll
    for (int i = 0; i < 8; ++i) {
      int c = tid + i * 256;
      int n = c >> 3, kc = c & 7;
      *reinterpret_cast<int4*>(&Bs[n][kc * 8]) =
          *reinterpret_cast<const int4*>(&w2t[n * 256 + k0 + kc * 8]);
    }
    __syncthreads();
#pragma unroll
    for (int kk = 0; kk < 2; ++kk) {
      bf16x8 af = *reinterpret_cast<const bf16x8*>(
          &As[waveM * 16 + l15][k0 + kk * 32 + g * 8]);
#pragma unroll
      for (int ni = 0; ni < 8; ++ni) {
        bf16x8 bfr = *reinterpret_cast<const bf16x8*>(
            &Bs[waveN * 128 + ni * 16 + l15][kk * 32 + g * 8]);
        acc[ni] = __builtin_amdgcn_mfma_f32_16x16x32_bf16(af, bfr, acc[ni], 0, 0, 0);
      }
    }
    __syncthreads();
  }
#pragma unroll
  for (int ni = 0; ni < 8; ++ni) {
    int col = waveN * 128 + ni * 16 + l15;
#pragma unroll
    for (int r = 0; r < 4; ++r) {
      int row = m0 + waveM * 16 + g * 4 + r;
      if (row < NN) out[row * 256 + col] = acc[ni][r] + bias2[ni];
    }
  }
}

// ---- launch ---------------------------------------------------------------

extern "C" void kernel_launch(void* const* d_in, const int* in_sizes, int n_in,
                              void* d_out, int out_size, void* d_ws, size_t ws_size,
                              hipStream_t stream) {
  const float* x = (const float*)d_in[0];
  const int* ei = (const int*)d_in[1];
  const float* w1 = (const float*)d_in[2];
  const float* b1 = (const float*)d_in[3];
  const float* w2 = (const float*)d_in[4];
  const float* b2 = (const float*)d_in[5];
  const float* eps = (const float*)d_in[6];
  float* out = (float*)d_out;

  // workspace layout (16B aligned throughout)
  int* cnt = (int*)d_ws;                              // 10240 ints
  int* bucket = cnt + 10240;                          // NN*CAP + 16 pad ints
  unsigned short* xb = (unsigned short*)(bucket + NN * CAP + 16);  // NN*256 bf16
  unsigned short* w1t = xb + NN * 256;                // 65536 bf16
  unsigned short* w2t = w1t + 65536;                  // 65536 bf16
  unsigned short* hb = w2t + 65536;                   // NN*256 bf16

  void* kargs[] = {(void*)&x,   (void*)&ei,     (void*)&w1,  (void*)&b1,
                   (void*)&w2,  (void*)&b2,     (void*)&eps, (void*)&out,
                   (void*)&cnt, (void*)&bucket, (void*)&xb,  (void*)&w1t,
                   (void*)&w2t, (void*)&hb};
  hipError_t err = hipLaunchCooperativeKernel((void*)mega2_k, dim3(CBLK),
                                              dim3(CTHR), kargs, 0, stream);
  if (err != hipSuccess) {
    // fallback: validated 4-dispatch path (rounds 3-5)
    conv_k<<<2532, 256, 0, stream>>>(x, w1, w2, (ushort4*)xb, w1t, w2t, cnt);
    fill_k<<<(NE / 4 + 255) / 256, 256, 0, stream>>>(ei, cnt, bucket);
    agg_k<<<(NN + 3) / 4, 256, 0, stream>>>((const ushort4*)xb, cnt, bucket, eps, hb);
    mlp_k<<<(NN + 31) / 32, 256, 0, stream>>>(hb, w1t, b1, w2t, b2, out);
  }
}

// Round 8
// 64.068 us; speedup vs baseline: 3.7214x; 3.7214x over previous
//
#include <hip/hip_runtime.h>

#define NN 10000
#define NE 320000
#define CAP 96

typedef __bf16 bf16x8 __attribute__((ext_vector_type(8)));
typedef float f32x4 __attribute__((ext_vector_type(4)));
typedef unsigned short us8 __attribute__((ext_vector_type(8)));

static __device__ __forceinline__ unsigned short f2bf(float f) {
  union { float fv; unsigned u; } v; v.fv = f;
  unsigned r = v.u + 0x7FFFu + ((v.u >> 16) & 1u);
  return (unsigned short)(r >> 16);
}
static __device__ __forceinline__ float bf2f(unsigned short b) {
  union { unsigned u; float f; } v; v.u = ((unsigned)b) << 16;
  return v.f;
}

// ---- conv: x->bf16 (blocks 0..2499), w1/w2 -> transposed bf16 via LDS tiles
//      (blocks 2500..2531), cnt zeroing folded in. (r3-validated) ----------

__global__ __launch_bounds__(256) void conv_k(const float* __restrict__ x,
                                              const float* __restrict__ w1,
                                              const float* __restrict__ w2,
                                              ushort4* __restrict__ xb4,
                                              unsigned short* __restrict__ w1t,
                                              unsigned short* __restrict__ w2t,
                                              int* __restrict__ cnt) {
  __shared__ unsigned short sh[64][72];
  int bid = blockIdx.x, tid = threadIdx.x;
  if (bid < 2500) {
    int t = bid * 256 + tid;
    if (t < 10240) cnt[t] = 0;
    float4 v = reinterpret_cast<const float4*>(x)[t];
    ushort4 o;
    o.x = f2bf(v.x); o.y = f2bf(v.y); o.z = f2bf(v.z); o.w = f2bf(v.w);
    xb4[t] = o;
  } else {
    int b2 = bid - 2500;                       // 0..31
    const float* w = (b2 & 16) ? w2 : w1;
    unsigned short* wt = (b2 & 16) ? w2t : w1t;
    int tile = b2 & 15;
    int ki0 = (tile >> 2) * 64, ni0 = (tile & 3) * 64;
    int r = tid >> 4, c = tid & 15;
#pragma unroll
    for (int rr = r; rr < 64; rr += 16) {      // coalesced f32x4 reads of w[k][n]
      float4 v = *reinterpret_cast<const float4*>(&w[(ki0 + rr) * 256 + ni0 + c * 4]);
      ushort4 o;
      o.x = f2bf(v.x); o.y = f2bf(v.y); o.z = f2bf(v.z); o.w = f2bf(v.w);
      *reinterpret_cast<ushort4*>(&sh[rr][c * 4]) = o;
    }
    __syncthreads();
    int n = tid >> 3, c8 = tid & 7;
#pragma unroll
    for (int nn = n; nn < 64; nn += 32) {      // coalesced 16B writes of wt[n][k]
      us8 o;
#pragma unroll
      for (int j = 0; j < 8; ++j) o[j] = sh[c8 * 8 + j][nn];
      *reinterpret_cast<us8*>(&wt[(ni0 + nn) * 256 + ki0 + c8 * 8]) = o;
    }
  }
}

// ---- bucket fill (4 edges / thread, r3-validated) -------------------------

__global__ __launch_bounds__(256) void fill_k(const int* __restrict__ ei,
                                              int* __restrict__ cnt,
                                              int* __restrict__ bucket) {
  int e = (blockIdx.x * 256 + threadIdx.x) * 4;
  if (e < NE) {
    int4 s = *reinterpret_cast<const int4*>(&ei[e]);
    int4 d = *reinterpret_cast<const int4*>(&ei[NE + e]);
    int p;
    p = atomicAdd(&cnt[d.x], 1); if (p < CAP) bucket[d.x * CAP + p] = s.x;
    p = atomicAdd(&cnt[d.y], 1); if (p < CAP) bucket[d.y * CAP + p] = s.y;
    p = atomicAdd(&cnt[d.z], 1); if (p < CAP) bucket[d.z * CAP + p] = s.z;
    p = atomicAdd(&cnt[d.w], 1); if (p < CAP) bucket[d.w * CAP + p] = s.w;
  }
}

// ---- aggregation v2: TWO waves per node, us8 (2-row) loads, idx prefetch --
// Block = 256 thr = 4 waves = 2 nodes. Wave pair splits the neighbor range
// [0,n0) / [n0,n); each wave: 32-lane x 16B row reads, 2 rows per inst
// (half=lane>>5 picks the row), 8 rows in flight. Partials combined via
// shfl_xor(32) then a 2KB LDS exchange. Halves the serial latency chain.

__global__ __launch_bounds__(256) void agg_k(const us8* __restrict__ xb8,
                                             const int* __restrict__ cnt,
                                             const int* __restrict__ bucket,
                                             const float* __restrict__ epsp,
                                             unsigned short* __restrict__ hb) {
  __shared__ float part[2][256];
  int tid = threadIdx.x;
  int wave = tid >> 6;
  int slot = wave >> 1;   // which node of the block's pair
  int p = wave & 1;       // which half of the neighbor range
  int node = blockIdx.x * 2 + slot;   // grid = NN/2 exactly
  int lane = tid & 63;
  int half = lane >> 5, off = lane & 31;
  float e1 = 1.0f + epsp[0];

  float a[8];
  if (p == 0) {
    us8 sv = xb8[node * 32 + off];
    float selfw = half ? 0.0f : e1;
#pragma unroll
    for (int j = 0; j < 8; ++j) a[j] = bf2f(sv[j]) * selfw;
  } else {
#pragma unroll
    for (int j = 0; j < 8; ++j) a[j] = 0.0f;
  }

  int n = min(cnt[node], CAP);
  int n0 = ((n + 4) >> 3) << 2;  // ~n/2 rounded to multiple of 4, never > n
  int s = p ? n0 : 0;
  int m = (p ? n : n0) - s;
  const int4* bp4 = reinterpret_cast<const int4*>(bucket + node * CAP + s);
  int4 ia = bp4[0], ib = bp4[1];
  int k = 0;
  while (k + 8 <= m) {
    int4 na = bp4[(k >> 2) + 2];  // prefetch next 8 indices (pad covers overreach)
    int4 nb = bp4[(k >> 2) + 3];
    int r0 = half ? ia.y : ia.x;
    int r1 = half ? ia.w : ia.z;
    int r2 = half ? ib.y : ib.x;
    int r3 = half ? ib.w : ib.z;
    us8 v0 = xb8[r0 * 32 + off];
    us8 v1 = xb8[r1 * 32 + off];
    us8 v2 = xb8[r2 * 32 + off];
    us8 v3 = xb8[r3 * 32 + off];
#pragma unroll
    for (int j = 0; j < 8; ++j)
      a[j] += (bf2f(v0[j]) + bf2f(v1[j])) + (bf2f(v2[j]) + bf2f(v3[j]));
    ia = na; ib = nb; k += 8;
  }
  int tl = m - k;  // 0..7 remaining, indices live in ia/ib
#pragma unroll
  for (int q = 0; q < 4; ++q) {
    int idx = (q == 0) ? (half ? ia.y : ia.x)
            : (q == 1) ? (half ? ia.w : ia.z)
            : (q == 2) ? (half ? ib.y : ib.x)
                       : (half ? ib.w : ib.z);
    if (2 * q + half < tl) {  // garbage idx never dereferenced
      us8 v = xb8[idx * 32 + off];
#pragma unroll
      for (int j = 0; j < 8; ++j) a[j] += bf2f(v[j]);
    }
  }
#pragma unroll
  for (int j = 0; j < 8; ++j) a[j] += __shfl_xor(a[j], 32);  // combine halves
  if (p == 1 && half == 0) {
#pragma unroll
    for (int j = 0; j < 8; ++j) part[slot][j * 32 + off] = a[j];
  }
  __syncthreads();
  if (p == 0 && half == 0) {
    us8 o;
#pragma unroll
    for (int j = 0; j < 8; ++j) o[j] = f2bf(a[j] + part[slot][j * 32 + off]);
    *reinterpret_cast<us8*>(&hb[node * 256 + off * 8]) = o;
  }
}

// ---- fused MLP: out = (relu(hb@W1+b1))@W2 + b2 (r3-validated) ------------

__global__ __launch_bounds__(256) void mlp_k(const unsigned short* __restrict__ hb,
                                             const unsigned short* __restrict__ w1t,
                                             const float* __restrict__ b1,
                                             const unsigned short* __restrict__ w2t,
                                             const float* __restrict__ b2,
                                             float* __restrict__ out) {
  __shared__ unsigned short As[32][264];
  __shared__ unsigned short Bs[256][72];
  int m0 = blockIdx.x * 32;
  int tid = threadIdx.x;
  int lane = tid & 63, wave = tid >> 6;
  int waveM = wave & 1, waveN = wave >> 1;
  int l15 = lane & 15, g = lane >> 4;
#pragma unroll
  for (int i = 0; i < 4; ++i) {
    int c = tid + i * 256;
    int r = c >> 5, cc = c & 31;
    int4 v = (m0 + r < NN)
                 ? *reinterpret_cast<const int4*>(&hb[(m0 + r) * 256 + cc * 8])
                 : make_int4(0, 0, 0, 0);
    *reinterpret_cast<int4*>(&As[r][cc * 8]) = v;
  }
  float bias1[8], bias2[8];
#pragma unroll
  for (int ni = 0; ni < 8; ++ni) {
    int col = waveN * 128 + ni * 16 + l15;
    bias1[ni] = b1[col];
    bias2[ni] = b2[col];
  }
  f32x4 acc[8];
#pragma unroll
  for (int ni = 0; ni < 8; ++ni) acc[ni] = f32x4{0.f, 0.f, 0.f, 0.f};
  for (int k0 = 0; k0 < 256; k0 += 64) {
#pragma unroll
    for (int i = 0; i < 8; ++i) {
      int c = tid + i * 256;
      int n = c >> 3, kc = c & 7;
      *reinterpret_cast<int4*>(&Bs[n][kc * 8]) =
          *reinterpret_cast<const int4*>(&w1t[n * 256 + k0 + kc * 8]);
    }
    __syncthreads();
#pragma unroll
    for (int kk = 0; kk < 2; ++kk) {
      bf16x8 af = *reinterpret_cast<const bf16x8*>(
          &As[waveM * 16 + l15][k0 + kk * 32 + g * 8]);
#pragma unroll
      for (int ni = 0; ni < 8; ++ni) {
        bf16x8 bfr = *reinterpret_cast<const bf16x8*>(
            &Bs[waveN * 128 + ni * 16 + l15][kk * 32 + g * 8]);
        acc[ni] = __builtin_amdgcn_mfma_f32_16x16x32_bf16(af, bfr, acc[ni], 0, 0, 0);
      }
    }
    __syncthreads();
  }
#pragma unroll
  for (int ni = 0; ni < 8; ++ni) {
    int col = waveN * 128 + ni * 16 + l15;
#pragma unroll
    for (int r = 0; r < 4; ++r) {
      int row = waveM * 16 + g * 4 + r;
      As[row][col] = f2bf(fmaxf(acc[ni][r] + bias1[ni], 0.f));
    }
    acc[ni] = f32x4{0.f, 0.f, 0.f, 0.f};
  }
  for (int k0 = 0; k0 < 256; k0 += 64) {
#pragma unroll
    for (int i = 0; i < 8; ++i) {
      int c = tid + i * 256;
      int n = c >> 3, kc = c & 7;
      *reinterpret_cast<int4*>(&Bs[n][kc * 8]) =
          *reinterpret_cast<const int4*>(&w2t[n * 256 + k0 + kc * 8]);
    }
    __syncthreads();
#pragma unroll
    for (int kk = 0; kk < 2; ++kk) {
      bf16x8 af = *reinterpret_cast<const bf16x8*>(
          &As[waveM * 16 + l15][k0 + kk * 32 + g * 8]);
#pragma unroll
      for (int ni = 0; ni < 8; ++ni) {
        bf16x8 bfr = *reinterpret_cast<const bf16x8*>(
            &Bs[waveN * 128 + ni * 16 + l15][kk * 32 + g * 8]);
        acc[ni] = __builtin_amdgcn_mfma_f32_16x16x32_bf16(af, bfr, acc[ni], 0, 0, 0);
      }
    }
    __syncthreads();
  }
#pragma unroll
  for (int ni = 0; ni < 8; ++ni) {
    int col = waveN * 128 + ni * 16 + l15;
#pragma unroll
    for (int r = 0; r < 4; ++r) {
      int row = m0 + waveM * 16 + g * 4 + r;
      if (row < NN) out[row * 256 + col] = acc[ni][r] + bias2[ni];
    }
  }
}

// ---- launch ---------------------------------------------------------------

extern "C" void kernel_launch(void* const* d_in, const int* in_sizes, int n_in,
                              void* d_out, int out_size, void* d_ws, size_t ws_size,
                              hipStream_t stream) {
  const float* x = (const float*)d_in[0];
  const int* ei = (const int*)d_in[1];
  const float* w1 = (const float*)d_in[2];
  const float* b1 = (const float*)d_in[3];
  const float* w2 = (const float*)d_in[4];
  const float* b2 = (const float*)d_in[5];
  const float* eps = (const float*)d_in[6];
  float* out = (float*)d_out;

  // workspace layout (16B aligned throughout)
  int* cnt = (int*)d_ws;                              // 10240 ints
  int* bucket = cnt + 10240;                          // NN*CAP ints + 32 pad
  unsigned short* xb = (unsigned short*)(bucket + NN * CAP + 32);  // NN*256 bf16
  unsigned short* w1t = xb + NN * 256;                // 65536 bf16
  unsigned short* w2t = w1t + 65536;                  // 65536 bf16
  unsigned short* hb = w2t + 65536;                   // NN*256 bf16

  conv_k<<<2532, 256, 0, stream>>>(x, w1, w2, (ushort4*)xb, w1t, w2t, cnt);
  fill_k<<<(NE / 4 + 255) / 256, 256, 0, stream>>>(ei, cnt, bucket);
  agg_k<<<NN / 2, 256, 0, stream>>>((const us8*)xb, cnt, bucket, eps, hb);
  mlp_k<<<(NN + 31) / 32, 256, 0, stream>>>(hb, w1t, b1, w2t, b2, out);
}